// Round 1
// baseline (56.769 us; speedup 1.0000x reference)
//
#include <hip/hip_runtime.h>
#include <hip/hip_bf16.h>
#include <stdint.h>

typedef short short8 __attribute__((ext_vector_type(8)));
typedef float f32x4 __attribute__((ext_vector_type(4)));
typedef unsigned short ushort4_t __attribute__((ext_vector_type(4)));

#define S_LEN 2048
#define NQKV 1536
#define DMODEL 512

__device__ inline unsigned short f2bf(float f) {
  unsigned int u = __float_as_uint(f);
  unsigned int r = (u + 0x7FFFu + ((u >> 16) & 1u)) >> 16;
  return (unsigned short)r;
}

// ---------------- conversion kernels ----------------
__global__ __launch_bounds__(256) void k_conv_x(const float* __restrict__ x,
                                                unsigned short* __restrict__ xb, int n) {
  int i = (blockIdx.x * 256 + threadIdx.x) * 4;
  if (i < n) {
    float4 v = *(const float4*)(x + i);
    ushort4_t o;
    o.x = f2bf(v.x); o.y = f2bf(v.y); o.z = f2bf(v.z); o.w = f2bf(v.w);
    *(ushort4_t*)(xb + i) = o;
  }
}

// W [rows][cols] f32  ->  Wt [cols][rows] bf16   (rows = K dim, cols = N dim)
__global__ __launch_bounds__(256) void k_convT(const float* __restrict__ w,
                                               unsigned short* __restrict__ wt,
                                               int rows, int cols) {
  __shared__ float T[32][33];
  int r0 = blockIdx.y * 32, c0 = blockIdx.x * 32;
  int tr = threadIdx.x / 32, tc = threadIdx.x % 32;  // tr 0..7
#pragma unroll
  for (int i = 0; i < 4; i++) {
    int r = tr + i * 8;
    T[r][tc] = w[(size_t)(r0 + r) * cols + c0 + tc];
  }
  __syncthreads();
#pragma unroll
  for (int i = 0; i < 4; i++) {
    int rr = tr + i * 8;  // output-row within the col-tile (n index)
    wt[(size_t)(c0 + rr) * rows + r0 + tc] = f2bf(T[tc][rr]);
  }
}

// ---------------- GEMM: C[M][N] = A[M][K](bf16) * Bt[N][K](bf16)^T ----------------
// 128x128 tile, BK=32, 4 waves (2x2), each wave 64x64 = 4x4 fragments of 16x16x32.
template <bool BF16_OUT>
__global__ __launch_bounds__(256) void k_gemm(const unsigned short* __restrict__ A,
                                              const unsigned short* __restrict__ Bt,
                                              void* __restrict__ Cout,
                                              const float* __restrict__ bias,
                                              int M, int N, int K) {
  __shared__ __align__(16) unsigned short As[128 * 40];
  __shared__ __align__(16) unsigned short Bs[128 * 40];
  const int t = threadIdx.x;
  const int lane = t & 63;
  const int wid = t >> 6;
  const int m0 = blockIdx.y * 128, n0 = blockIdx.x * 128;
  const int wm = (wid >> 1) * 64, wn = (wid & 1) * 64;

  f32x4 acc[4][4] = {};

  const int ra0 = t >> 2, pa0 = (t & 3) * 8;
  const int c1 = t + 256;
  const int ra1 = c1 >> 2, pa1 = (c1 & 3) * 8;
  const unsigned short* Ab = A + (size_t)m0 * K;
  const unsigned short* Bb = Bt + (size_t)n0 * K;

  const int lr = lane & 15;
  const int kr = (lane >> 4) * 8;

  for (int kt = 0; kt < K; kt += 32) {
    short8 va0 = *(const short8*)(Ab + (size_t)ra0 * K + kt + pa0);
    short8 va1 = *(const short8*)(Ab + (size_t)ra1 * K + kt + pa1);
    short8 vb0 = *(const short8*)(Bb + (size_t)ra0 * K + kt + pa0);
    short8 vb1 = *(const short8*)(Bb + (size_t)ra1 * K + kt + pa1);
    __syncthreads();  // previous compute done before overwriting LDS
    *(short8*)&As[ra0 * 40 + pa0] = va0;
    *(short8*)&As[ra1 * 40 + pa1] = va1;
    *(short8*)&Bs[ra0 * 40 + pa0] = vb0;
    *(short8*)&Bs[ra1 * 40 + pa1] = vb1;
    __syncthreads();

    short8 af[4], bfr[4];
#pragma unroll
    for (int i = 0; i < 4; i++)
      af[i] = *(const short8*)&As[(wm + i * 16 + lr) * 40 + kr];
#pragma unroll
    for (int i = 0; i < 4; i++)
      bfr[i] = *(const short8*)&Bs[(wn + i * 16 + lr) * 40 + kr];
#pragma unroll
    for (int mi = 0; mi < 4; mi++)
#pragma unroll
      for (int ni = 0; ni < 4; ni++)
        acc[mi][ni] = __builtin_amdgcn_mfma_f32_16x16x32_bf16(af[mi], bfr[ni], acc[mi][ni], 0, 0, 0);
  }

  const int lg = lane >> 4;
#pragma unroll
  for (int mi = 0; mi < 4; mi++) {
#pragma unroll
    for (int ni = 0; ni < 4; ni++) {
      int col = n0 + wn + ni * 16 + lr;
      float bv = BF16_OUT ? 0.0f : bias[col];
#pragma unroll
      for (int j = 0; j < 4; j++) {
        int row = m0 + wm + mi * 16 + lg * 4 + j;
        float v = acc[mi][ni][j];
        if (BF16_OUT)
          ((unsigned short*)Cout)[(size_t)row * N + col] = f2bf(v);
        else
          ((float*)Cout)[(size_t)row * N + col] = v + bv;
      }
    }
  }
}

// ---------------- windowed attention ----------------
// Block: 256 thr = 4 waves; block covers (b, h, 64 queries); each wave 16 queries.
// qkv layout: [b*S + s][h*192 + {0..63 q | 64..127 k | 128..191 v}] bf16.
__global__ __launch_bounds__(256) void k_attn(const unsigned short* __restrict__ qkv,
                                              unsigned short* __restrict__ attn) {
  __shared__ __align__(16) unsigned short Vt[64][136];     // V^T: [d][pos-local 0..127]
  __shared__ __align__(16) unsigned short Pl[4][16 * 104]; // per-wave P: [16 q][96 k +pad]
  const int t = threadIdx.x, lane = t & 63, w = t >> 6;
  const int blk = blockIdx.x;
  const int sbi = blk & 31, h = (blk >> 5) & 7, b = blk >> 8;
  const int sb = sbi * 64;
  const unsigned short* base = qkv + (size_t)b * S_LEN * NQKV;
  const int lr = lane & 15, lg = lane >> 4;
  const int s0 = sb + w * 16;

  // Q fragments (A-layout): lane holds Q[s0 + lr][ks*32 + lg*8 .. +7]
  short8 qa[2];
#pragma unroll
  for (int ks = 0; ks < 2; ks++)
    qa[ks] = *(const short8*)(base + (size_t)(s0 + lr) * NQKV + h * 192 + ks * 32 + lg * 8);

  // Stage V^T for pos sb-32 .. sb+95 (128 rows), zero outside [0,S)
#pragma unroll
  for (int i = 0; i < 4; i++) {
    int f = t + 256 * i;
    int row = f >> 3, dcol = (f & 7) * 8;
    int gp = sb - 32 + row;
    short8 v = {};
    if (gp >= 0 && gp < S_LEN)
      v = *(const short8*)(base + (size_t)gp * NQKV + h * 192 + 128 + dcol);
#pragma unroll
    for (int j = 0; j < 8; j++) Vt[dcol + j][row] = (unsigned short)v[j];
  }

  // Scores: 5 col-tiles of 16 keys, K=64 -> 2 MFMA each. B-frag gathered from global.
  f32x4 sc[5] = {};
#pragma unroll
  for (int ct = 0; ct < 5; ct++) {
    int p = s0 - 32 + ct * 16 + lr;  // global key position for this lane's column
#pragma unroll
    for (int ks = 0; ks < 2; ks++) {
      short8 kb = {};
      if (p >= 0 && p < S_LEN)
        kb = *(const short8*)(base + (size_t)p * NQKV + h * 192 + 64 + ks * 32 + lg * 8);
      sc[ct] = __builtin_amdgcn_mfma_f32_16x16x32_bf16(qa[ks], kb, sc[ct], 0, 0, 0);
    }
  }

  __syncthreads();  // Vt staged; P regions free

  // Band mask + scale. C layout: row q = lg*4+j, col c = ct*16+lr.
  // valid window: 0 <= c - r <= 64 ; out-of-range pos already give score 0 (zero k).
#pragma unroll
  for (int ct = 0; ct < 5; ct++)
#pragma unroll
    for (int j = 0; j < 4; j++) {
      int c = ct * 16 + lr, r = lg * 4 + j;
      sc[ct][j] = (c >= r && c <= r + 64) ? sc[ct][j] * 0.125f : -1e30f;
    }

  float inv[4];
#pragma unroll
  for (int j = 0; j < 4; j++) {
    float m = fmaxf(fmaxf(fmaxf(sc[0][j], sc[1][j]), fmaxf(sc[2][j], sc[3][j])), sc[4][j]);
#pragma unroll
    for (int d = 1; d < 16; d <<= 1) m = fmaxf(m, __shfl_xor(m, d, 64));
#pragma unroll
    for (int ct = 0; ct < 5; ct++) sc[ct][j] = __expf(sc[ct][j] - m);
    float s = sc[0][j] + sc[1][j] + sc[2][j] + sc[3][j] + sc[4][j];
#pragma unroll
    for (int d = 1; d < 16; d <<= 1) s += __shfl_xor(s, d, 64);
    inv[j] = 1.0f / s;
  }

  // Write P (bf16) into per-wave LDS for transpose to A-layout; zero cols 80..95.
  unsigned short* P = &Pl[w][0];
#pragma unroll
  for (int ct = 0; ct < 5; ct++)
#pragma unroll
    for (int j = 0; j < 4; j++)
      P[(lg * 4 + j) * 104 + ct * 16 + lr] = f2bf(sc[ct][j] * inv[j]);
  {
    int r = lane & 15, cb = 80 + (lane >> 4) * 4;
#pragma unroll
    for (int j = 0; j < 4; j++) P[r * 104 + cb + j] = 0;
  }
  __syncthreads();

  // PV: P (16x96) * V (96x64). A-frag from P LDS, B-frag from Vt LDS.
  f32x4 oa[4] = {};
#pragma unroll
  for (int ks = 0; ks < 3; ks++) {
    short8 pa = *(const short8*)&P[lr * 104 + ks * 32 + lg * 8];
#pragma unroll
    for (int nt = 0; nt < 4; nt++) {
      short8 vb = {};
      if (ks < 2 || lg < 2)  // cols >= 128 have P==0; avoid OOB Vt reads
        vb = *(const short8*)&Vt[lr + nt * 16][w * 16 + ks * 32 + lg * 8];
      oa[nt] = __builtin_amdgcn_mfma_f32_16x16x32_bf16(pa, vb, oa[nt], 0, 0, 0);
    }
  }

  // Store attn [b*S + q][h*64 + d] bf16
#pragma unroll
  for (int nt = 0; nt < 4; nt++) {
    int d = lr + nt * 16;
#pragma unroll
    for (int j = 0; j < 4; j++) {
      int q = lg * 4 + j;
      attn[((size_t)b * S_LEN + s0 + q) * DMODEL + h * 64 + d] = f2bf(oa[nt][j]);
    }
  }
}

// ---------------- launch ----------------
extern "C" void kernel_launch(void* const* d_in, const int* in_sizes, int n_in,
                              void* d_out, int out_size, void* d_ws, size_t ws_size,
                              hipStream_t stream) {
  const float* x    = (const float*)d_in[0];
  const float* Wqkv = (const float*)d_in[1];
  const float* Wout = (const float*)d_in[2];
  const float* bout = (const float*)d_in[3];
  char* ws = (char*)d_ws;
  unsigned short* xb    = (unsigned short*)(ws + 0);         // 4096x512 bf16  (4 MB)
  unsigned short* wqkvt = (unsigned short*)(ws + 4194304);   // 1536x512 bf16  (1.5 MB)
  unsigned short* woutt = (unsigned short*)(ws + 5767168);   // 512x512  bf16  (0.5 MB)
  unsigned short* qkv   = (unsigned short*)(ws + 6291456);   // 4096x1536 bf16 (12 MB)
  unsigned short* attn  = (unsigned short*)(ws + 18874368);  // 4096x512 bf16  (4 MB)
  float* out = (float*)d_out;

  hipLaunchKernelGGL(k_conv_x, dim3(2048), dim3(256), 0, stream, x, xb, 4096 * 512);
  hipLaunchKernelGGL(k_convT, dim3(48, 16), dim3(256), 0, stream, Wqkv, wqkvt, 512, 1536);
  hipLaunchKernelGGL(k_convT, dim3(16, 16), dim3(256), 0, stream, Wout, woutt, 512, 512);
  hipLaunchKernelGGL((k_gemm<true>), dim3(12, 32), dim3(256), 0, stream,
                     xb, wqkvt, (void*)qkv, (const float*)nullptr, 4096, 1536, 512);
  hipLaunchKernelGGL(k_attn, dim3(512), dim3(256), 0, stream, qkv, attn);
  hipLaunchKernelGGL((k_gemm<false>), dim3(4, 32), dim3(256), 0, stream,
                     attn, woutt, d_out, bout, 4096, 512, 512);
}

// Round 2
// 49.521 us; speedup vs baseline: 1.1464x; 1.1464x over previous
//
#include <hip/hip_runtime.h>
#include <hip/hip_bf16.h>
#include <stdint.h>

typedef short short8 __attribute__((ext_vector_type(8)));
typedef float f32x4 __attribute__((ext_vector_type(4)));
typedef unsigned short ushort8_t __attribute__((ext_vector_type(8)));

#define S_LEN 2048
#define NQKV 1536
#define DMODEL 512

__device__ inline unsigned short f2bf(float f) {
  unsigned int u = __float_as_uint(f);
  unsigned int r = (u + 0x7FFFu + ((u >> 16) & 1u)) >> 16;
  return (unsigned short)r;
}

// async global->LDS, 16B per lane. LDS dest must be linear in lane order.
__device__ __forceinline__ void gll16(const unsigned short* g, unsigned short* l) {
  __builtin_amdgcn_global_load_lds(
      (const __attribute__((address_space(1))) unsigned int*)g,
      (__attribute__((address_space(3))) unsigned int*)l, 16, 0, 0);
}

// ---------------- conversion kernels ----------------
__global__ __launch_bounds__(256) void k_conv_x(const float* __restrict__ x,
                                                unsigned short* __restrict__ xb) {
  int i = (blockIdx.x * 256 + threadIdx.x) * 8;
  float4 a = *(const float4*)(x + i);
  float4 b = *(const float4*)(x + i + 4);
  ushort8_t o;
  o[0] = f2bf(a.x); o[1] = f2bf(a.y); o[2] = f2bf(a.z); o[3] = f2bf(a.w);
  o[4] = f2bf(b.x); o[5] = f2bf(b.y); o[6] = f2bf(b.z); o[7] = f2bf(b.w);
  *(ushort8_t*)(xb + i) = o;
}

// Both weight transposes in one launch.
// W [rows=512][cols] f32 -> Wt [cols][rows=512] bf16.
__global__ __launch_bounds__(256) void k_convW(const float* __restrict__ w1,
                                               unsigned short* __restrict__ o1,
                                               const float* __restrict__ w2,
                                               unsigned short* __restrict__ o2) {
  __shared__ float T[32][33];
  int bx = blockIdx.x;
  const float* w; unsigned short* o; int cols;
  if (bx < 48) { w = w1; o = o1; cols = 1536; }
  else         { w = w2; o = o2; cols = 512; bx -= 48; }
  int r0 = blockIdx.y * 32, c0 = bx * 32;
  int tr = threadIdx.x / 32, tc = threadIdx.x % 32;
#pragma unroll
  for (int i = 0; i < 4; i++) {
    int r = tr + i * 8;
    T[r][tc] = w[(size_t)(r0 + r) * cols + c0 + tc];
  }
  __syncthreads();
#pragma unroll
  for (int i = 0; i < 4; i++) {
    int rr = tr + i * 8;
    o[(size_t)(c0 + rr) * 512 + r0 + tc] = f2bf(T[tc][rr]);
  }
}

// ---------------- GEMM: C[M][N] = A[M][K](bf16) * Bt[N][K](bf16)^T ----------------
// BMx128 tile, BK=32, 4 waves, global_load_lds staging, 2-phase double buffer.
template <int BM, bool BF16_OUT>
__global__ __launch_bounds__(256) void k_gemm(const unsigned short* __restrict__ A,
                                              const unsigned short* __restrict__ Bt,
                                              void* __restrict__ Cout,
                                              const float* __restrict__ bias,
                                              int M, int N, int K) {
  constexpr int MR = BM / 32;   // A-frags per wave (4 or 2)
  constexpr int CA = BM / 64;   // gload calls per thread for A (2 or 1)
  __shared__ __align__(16) unsigned short As[2][BM * 32];
  __shared__ __align__(16) unsigned short Bs[2][128 * 32];
  const int t = threadIdx.x, lane = t & 63, wid = t >> 6;
  const int m0 = blockIdx.y * BM, n0 = blockIdx.x * 128;
  const int wm = (wid >> 1) * (BM / 2), wn = (wid & 1) * 64;
  const int lr = lane & 15, kr = (lane >> 4) * 8, lg = lane >> 4;
  const unsigned short* Ab = A + (size_t)m0 * K;
  const unsigned short* Bb = Bt + (size_t)n0 * K;
  f32x4 acc[MR][4] = {};

  const int NT = K / 32;
  auto stage = [&](int buf, int kt) {
#pragma unroll
    for (int c = 0; c < CA; c++) {
      int f = t + 256 * c;
      gll16(Ab + (size_t)(f >> 2) * K + kt + (f & 3) * 8, &As[buf][f * 8]);
    }
#pragma unroll
    for (int c = 0; c < 2; c++) {
      int f = t + 256 * c;
      gll16(Bb + (size_t)(f >> 2) * K + kt + (f & 3) * 8, &Bs[buf][f * 8]);
    }
  };

  stage(0, 0);
  int buf = 0;
  for (int it = 0; it < NT; ++it) {
    __syncthreads();  // drains prefetch (vmcnt0) + protects buf^1 from overwrite
    if (it + 1 < NT) stage(buf ^ 1, (it + 1) * 32);
    short8 af[MR], bfv[4];
#pragma unroll
    for (int i = 0; i < MR; i++)
      af[i] = *(const short8*)&As[buf][(wm + i * 16 + lr) * 32 + kr];
#pragma unroll
    for (int i = 0; i < 4; i++)
      bfv[i] = *(const short8*)&Bs[buf][(wn + i * 16 + lr) * 32 + kr];
#pragma unroll
    for (int mi = 0; mi < MR; mi++)
#pragma unroll
      for (int ni = 0; ni < 4; ni++)
        acc[mi][ni] = __builtin_amdgcn_mfma_f32_16x16x32_bf16(af[mi], bfv[ni], acc[mi][ni], 0, 0, 0);
    buf ^= 1;
  }

#pragma unroll
  for (int mi = 0; mi < MR; mi++) {
#pragma unroll
    for (int ni = 0; ni < 4; ni++) {
      int col = n0 + wn + ni * 16 + lr;
      float bv = BF16_OUT ? 0.0f : bias[col];
#pragma unroll
      for (int j = 0; j < 4; j++) {
        int row = m0 + wm + mi * 16 + lg * 4 + j;
        float v = acc[mi][ni][j];
        if (BF16_OUT)
          ((unsigned short*)Cout)[(size_t)row * N + col] = f2bf(v);
        else
          ((float*)Cout)[(size_t)row * N + col] = v + bv;
      }
    }
  }
}

// ---------------- windowed attention ----------------
// Block: 256 thr = 4 waves; block covers (b, h, 64 queries); each wave 16 queries.
// qkv layout: [b*S + s][h*192 + {0..63 q | 64..127 k | 128..191 v}] bf16.
__global__ __launch_bounds__(256) void k_attn(const unsigned short* __restrict__ qkv,
                                              unsigned short* __restrict__ attn) {
  __shared__ __align__(16) unsigned short Vt[64][136];     // V^T: [d][pos-local 0..127]
  __shared__ __align__(16) unsigned short Pl[4][16 * 104]; // per-wave P: [16 q][96 k +pad]
  const int t = threadIdx.x, lane = t & 63, w = t >> 6;
  const int blk = blockIdx.x;
  const int sbi = blk & 31, h = (blk >> 5) & 7, b = blk >> 8;
  const int sb = sbi * 64;
  const unsigned short* base = qkv + (size_t)b * S_LEN * NQKV;
  const int lr = lane & 15, lg = lane >> 4;
  const int s0 = sb + w * 16;

  // Q fragments (A-layout): lane holds Q[s0 + lr][ks*32 + lg*8 .. +7]
  short8 qa[2];
#pragma unroll
  for (int ks = 0; ks < 2; ks++)
    qa[ks] = *(const short8*)(base + (size_t)(s0 + lr) * NQKV + h * 192 + ks * 32 + lg * 8);

  // Stage V^T for pos sb-32 .. sb+95 (128 rows), zero outside [0,S)
#pragma unroll
  for (int i = 0; i < 4; i++) {
    int f = t + 256 * i;
    int row = f >> 3, dcol = (f & 7) * 8;
    int gp = sb - 32 + row;
    short8 v = {};
    if (gp >= 0 && gp < S_LEN)
      v = *(const short8*)(base + (size_t)gp * NQKV + h * 192 + 128 + dcol);
#pragma unroll
    for (int j = 0; j < 8; j++) Vt[dcol + j][row] = (unsigned short)v[j];
  }

  // Scores: 5 col-tiles of 16 keys, K=64 -> 2 MFMA each. B-frag gathered from global.
  f32x4 sc[5] = {};
#pragma unroll
  for (int ct = 0; ct < 5; ct++) {
    int p = s0 - 32 + ct * 16 + lr;
#pragma unroll
    for (int ks = 0; ks < 2; ks++) {
      short8 kb = {};
      if (p >= 0 && p < S_LEN)
        kb = *(const short8*)(base + (size_t)p * NQKV + h * 192 + 64 + ks * 32 + lg * 8);
      sc[ct] = __builtin_amdgcn_mfma_f32_16x16x32_bf16(qa[ks], kb, sc[ct], 0, 0, 0);
    }
  }

  __syncthreads();  // Vt staged

  // Band mask + scale. C layout: row q = lg*4+j, col c = ct*16+lr.
#pragma unroll
  for (int ct = 0; ct < 5; ct++)
#pragma unroll
    for (int j = 0; j < 4; j++) {
      int c = ct * 16 + lr, r = lg * 4 + j;
      sc[ct][j] = (c >= r && c <= r + 64) ? sc[ct][j] * 0.125f : -1e30f;
    }

  float inv[4];
#pragma unroll
  for (int j = 0; j < 4; j++) {
    float m = fmaxf(fmaxf(fmaxf(sc[0][j], sc[1][j]), fmaxf(sc[2][j], sc[3][j])), sc[4][j]);
#pragma unroll
    for (int d = 1; d < 16; d <<= 1) m = fmaxf(m, __shfl_xor(m, d, 64));
#pragma unroll
    for (int ct = 0; ct < 5; ct++) sc[ct][j] = __expf(sc[ct][j] - m);
    float s = sc[0][j] + sc[1][j] + sc[2][j] + sc[3][j] + sc[4][j];
#pragma unroll
    for (int d = 1; d < 16; d <<= 1) s += __shfl_xor(s, d, 64);
    inv[j] = 1.0f / s;
  }

  // Write P (bf16) into per-wave LDS for transpose to A-layout; zero cols 80..95.
  unsigned short* P = &Pl[w][0];
#pragma unroll
  for (int ct = 0; ct < 5; ct++)
#pragma unroll
    for (int j = 0; j < 4; j++)
      P[(lg * 4 + j) * 104 + ct * 16 + lr] = f2bf(sc[ct][j] * inv[j]);
  {
    int r = lane & 15, cb = 80 + (lane >> 4) * 4;
#pragma unroll
    for (int j = 0; j < 4; j++) P[r * 104 + cb + j] = 0;
  }
  __syncthreads();

  // PV: P (16x96) * V (96x64). A-frag from P LDS, B-frag from Vt LDS.
  f32x4 oa[4] = {};
#pragma unroll
  for (int ks = 0; ks < 3; ks++) {
    short8 pa = *(const short8*)&P[lr * 104 + ks * 32 + lg * 8];
#pragma unroll
    for (int nt = 0; nt < 4; nt++) {
      short8 vb = {};
      if (ks < 2 || lg < 2)
        vb = *(const short8*)&Vt[lr + nt * 16][w * 16 + ks * 32 + lg * 8];
      oa[nt] = __builtin_amdgcn_mfma_f32_16x16x32_bf16(pa, vb, oa[nt], 0, 0, 0);
    }
  }

#pragma unroll
  for (int nt = 0; nt < 4; nt++) {
    int d = lr + nt * 16;
#pragma unroll
    for (int j = 0; j < 4; j++) {
      int q = lg * 4 + j;
      attn[((size_t)b * S_LEN + s0 + q) * DMODEL + h * 64 + d] = f2bf(oa[nt][j]);
    }
  }
}

// ---------------- launch ----------------
extern "C" void kernel_launch(void* const* d_in, const int* in_sizes, int n_in,
                              void* d_out, int out_size, void* d_ws, size_t ws_size,
                              hipStream_t stream) {
  const float* x    = (const float*)d_in[0];
  const float* Wqkv = (const float*)d_in[1];
  const float* Wout = (const float*)d_in[2];
  const float* bout = (const float*)d_in[3];
  char* ws = (char*)d_ws;
  unsigned short* xb    = (unsigned short*)(ws + 0);         // 4096x512 bf16  (4 MB)
  unsigned short* wqkvt = (unsigned short*)(ws + 4194304);   // 1536x512 bf16  (1.5 MB)
  unsigned short* woutt = (unsigned short*)(ws + 5767168);   // 512x512  bf16  (0.5 MB)
  unsigned short* qkv   = (unsigned short*)(ws + 6291456);   // 4096x1536 bf16 (12 MB)
  unsigned short* attn  = (unsigned short*)(ws + 18874368);  // 4096x512 bf16  (4 MB)

  hipLaunchKernelGGL(k_conv_x, dim3(1024), dim3(256), 0, stream, x, xb);
  hipLaunchKernelGGL(k_convW, dim3(64, 16), dim3(256), 0, stream, Wqkv, wqkvt, Wout, woutt);
  hipLaunchKernelGGL((k_gemm<128, true>), dim3(12, 32), dim3(256), 0, stream,
                     xb, wqkvt, (void*)qkv, (const float*)nullptr, 4096, 1536, 512);
  hipLaunchKernelGGL(k_attn, dim3(512), dim3(256), 0, stream, qkv, attn);
  hipLaunchKernelGGL((k_gemm<64, false>), dim3(4, 64), dim3(256), 0, stream,
                     attn, woutt, d_out, bout, 4096, 512, 512);
}